// Round 9
// baseline (500.776 us; speedup 1.0000x reference)
//
#include <hip/hip_runtime.h>
#include <stdint.h>

#define BN_EPS 1e-5f
#define CHUNK 4096

typedef __attribute__((ext_vector_type(8))) short s16x8;
typedef __attribute__((ext_vector_type(16))) float f32x16;
typedef __attribute__((ext_vector_type(4))) unsigned short u16x4;
typedef unsigned short ushort_t;
typedef _Float16 f16;
typedef __attribute__((ext_vector_type(4))) _Float16 f16x4;

__device__ __forceinline__ ushort_t f2bf(float x) {
    uint32_t u = __float_as_uint(x);
    u += 0x7fff + ((u >> 16) & 1);   // round-to-nearest-even
    return (ushort_t)(u >> 16);
}
__device__ __forceinline__ float bf2f(ushort_t h) {
    return __uint_as_float(((uint32_t)h) << 16);
}

// ---------------- weight prep: f32 [k][col] -> bf16 hi/lo planes in FRAGMENT ORDER ----
// plane layout: [wv(4)][ks(8)][lane(64)][j(8)]  (col = wv*32+(lane&31), k = ks*16+(lane>>5)*8+j)
// -> every fragment load in k_mlp is a coalesced 16B/lane run (1KB per wave).
__global__ void k_wprep(const float* __restrict__ w0, const float* __restrict__ w1,
                        const float* __restrict__ w2, const float* __restrict__ w3,
                        ushort_t* __restrict__ wpl) {
    int mat = blockIdx.x >> 6;
    const float* w = (mat == 0) ? w0 : (mat == 1) ? w1 : (mat == 2) ? w2 : w3;
    int e = ((blockIdx.x & 63) << 8) + threadIdx.x;   // 0..16383
    int k = e >> 7, col = e & 127;
    float v = w[e];
    ushort_t h = f2bf(v);
    ushort_t l = f2bf(v - bf2f(h));
    int wv = col >> 5, ks = k >> 4, hf = (k >> 3) & 1, j = k & 7;
    int lane = (hf << 5) + (col & 31);
    int idx = ((((wv << 3) + ks) << 6) + lane) << 3;   // *8 elems
    ushort_t* base = wpl + (size_t)mat * 32768;
    base[idx + j] = h;
    base[16384 + idx + j] = l;
}

// ---------------- fp16 gather-plane prep ----------------
__global__ void k_x0(const float* __restrict__ in, f16* __restrict__ out, int n4) {
    int i = blockIdx.x * blockDim.x + threadIdx.x;
    int st = gridDim.x * blockDim.x;
    for (; i < n4; i += st) {
        float4 v = ((const float4*)in)[i];
        f16x4 h;
        h[0] = (f16)v.x; h[1] = (f16)v.y; h[2] = (f16)v.z; h[3] = (f16)v.w;
        ((f16x4*)out)[i] = h;
    }
}

__global__ __launch_bounds__(256) void k_x1(const float* __restrict__ h2, const float* __restrict__ stats,
                                            const float* __restrict__ gamma, const float* __restrict__ beta,
                                            float invN, f16* __restrict__ out, int n4) {
    __shared__ float sc[128], sh[128];
    int t = threadIdx.x;
    if (t < 128) {
        float mean = stats[t] * invN;
        float var = stats[128 + t] * invN - mean * mean;
        float s = gamma[t] * rsqrtf(var + BN_EPS);
        sc[t] = s; sh[t] = beta[t] - mean * s;
    }
    __syncthreads();
    int i = blockIdx.x * 256 + t, st = gridDim.x * 256;
    for (; i < n4; i += st) {
        float4 v = ((const float4*)h2)[i];
        int c = (i << 2) & 127;
        f16x4 h;
        h[0] = (f16)fmaxf(v.x * sc[c + 0] + sh[c + 0], 0.f);
        h[1] = (f16)fmaxf(v.y * sc[c + 1] + sh[c + 1], 0.f);
        h[2] = (f16)fmaxf(v.z * sc[c + 2] + sh[c + 2], 0.f);
        h[3] = (f16)fmaxf(v.w * sc[c + 3] + sh[c + 3], 0.f);
        ((f16x4*)out)[i] = h;
    }
}

// ---------------- binned CSR build ----------------
__global__ __launch_bounds__(256) void k_bin(const int* __restrict__ src, const int* __restrict__ dst,
                                             int E, int NBUK, int CAP,
                                             int* __restrict__ gcursor, uint32_t* __restrict__ binned) {
    __shared__ int hist[128], excl[128], gbase[128], hA[128], hB[128];
    __shared__ uint32_t pbuf[CHUNK];
    __shared__ unsigned char bbuf[CHUNK];
    int t = threadIdx.x;
    int base = blockIdx.x * CHUNK;
    int cnt = E - base; if (cnt > CHUNK) cnt = CHUNK;

    uint32_t pk[16]; int bk[16]; int loc[16];
    if (t < 128) hist[t] = 0;
    __syncthreads();
#pragma unroll
    for (int k = 0; k < 16; ++k) {
        int j = t + (k << 8);
        bk[k] = -1;
        if (j < cnt) {
            int s = src[base + j], d = dst[base + j];
            bk[k] = d >> 10;
            pk[k] = ((uint32_t)s << 10) | (uint32_t)(d & 1023);
            loc[k] = atomicAdd(&hist[bk[k]], 1);
        }
    }
    __syncthreads();
    if (t < 128) hA[t] = (t < NBUK) ? hist[t] : 0;
    __syncthreads();
    {
        int cb = 0;
        int* bufs[2] = {hA, hB};
        for (int off = 1; off < 128; off <<= 1) {
            int* A = bufs[cb]; int* B = bufs[cb ^ 1];
            if (t < 128) B[t] = A[t] + ((t >= off) ? A[t - off] : 0);
            __syncthreads();
            cb ^= 1;
        }
        if (t < 128) excl[t] = bufs[cb][t] - ((t < NBUK) ? hist[t] : 0);
    }
    if (t < NBUK && hist[t] > 0) gbase[t] = atomicAdd(&gcursor[t], hist[t]);
    __syncthreads();
#pragma unroll
    for (int k = 0; k < 16; ++k) {
        if (bk[k] >= 0) {
            int slot = excl[bk[k]] + loc[k];
            pbuf[slot] = pk[k];
            bbuf[slot] = (unsigned char)bk[k];
        }
    }
    __syncthreads();
    for (int j = t; j < cnt; j += 256) {
        int b = bbuf[j];
        int pos = gbase[b] + (j - excl[b]);
        if (pos < CAP) binned[(size_t)b * CAP + pos] = pbuf[j];
    }
}

__global__ void k_bucketscan(const int* __restrict__ gcursor, int NBUK,
                             int* __restrict__ bucketBase, int* __restrict__ rowstart,
                             int N, int E) {
    __shared__ int hA[128], hB[128];
    int t = threadIdx.x;   // 128
    int v = (t < NBUK) ? gcursor[t] : 0;
    hA[t] = v;
    __syncthreads();
    int cb = 0;
    int* bufs[2] = {hA, hB};
    for (int off = 1; off < 128; off <<= 1) {
        int* A = bufs[cb]; int* B = bufs[cb ^ 1];
        B[t] = A[t] + ((t >= off) ? A[t - off] : 0);
        __syncthreads();
        cb ^= 1;
    }
    if (t < NBUK) bucketBase[t] = bufs[cb][t] - v;
    if (t == 0) rowstart[N] = E;
}

__global__ __launch_bounds__(1024) void k_bucketcsr(const uint32_t* __restrict__ binned,
                                                    const int* __restrict__ gcursor,
                                                    const int* __restrict__ bucketBase,
                                                    int CAP, int N,
                                                    int* __restrict__ rowstart, int* __restrict__ csr) {
    __shared__ int deg[1024], sA[1024], sB[1024], cur[1024];
    int b = blockIdx.x, t = threadIdx.x;
    int cnt = gcursor[b]; if (cnt > CAP) cnt = CAP;
    int gb = bucketBase[b];
    int nodeBase = b << 10;
    int nloc = N - nodeBase; if (nloc > 1024) nloc = 1024;
    const uint32_t* eb = binned + (size_t)b * CAP;

    deg[t] = 0;
    __syncthreads();
    for (int j = t; j < cnt; j += 1024) atomicAdd(&deg[eb[j] & 1023], 1);
    __syncthreads();
    sA[t] = deg[t];
    __syncthreads();
    int cb2 = 0;
    int* bufs[2] = {sA, sB};
    for (int off = 1; off < 1024; off <<= 1) {
        int* A = bufs[cb2]; int* B = bufs[cb2 ^ 1];
        B[t] = A[t] + ((t >= off) ? A[t - off] : 0);
        __syncthreads();
        cb2 ^= 1;
    }
    int ex = bufs[cb2][t] - deg[t];
    cur[t] = ex;
    if (t < nloc) rowstart[nodeBase + t] = gb + ex;
    __syncthreads();
    for (int j = t; j < cnt; j += 1024) {
        uint32_t e = eb[j];
        int p = atomicAdd(&cur[e & 1023], 1);
        csr[gb + p] = (int)(e >> 10);
    }
}

// ---------------- aggregation: out = plane[n] + sum_nbr plane[s]  (plane = fp16) --------
__global__ __launch_bounds__(256) void k_agg(const f16* __restrict__ plane, int N,
                                             const int* __restrict__ rowstart, const int* __restrict__ csr,
                                             ushort_t* __restrict__ out_hi, ushort_t* __restrict__ out_lo) {
    int node = (int)((blockIdx.x * (size_t)blockDim.x + threadIdx.x) >> 6);
    int lane = threadIdx.x & 63;
    int half = lane >> 5, li = lane & 31, ch4 = li << 2;
    if (node >= N) return;

    float ax = 0.f, ay = 0.f, az = 0.f, aw = 0.f;
    if (half == 0) {
        f16x4 sv = *(const f16x4*)(plane + (size_t)node * 128 + ch4);
        ax = (float)sv[0]; ay = (float)sv[1]; az = (float)sv[2]; aw = (float)sv[3];
    }

    int s0 = rowstart[node], s1 = rowstart[node + 1];
    for (int base2 = s0; base2 < s1; base2 += 64) {
        int m = s1 - base2; if (m > 64) m = 64;
        int idx = (lane < m) ? csr[base2 + lane] : 0;
        for (int j = 0; j < m; j += 8) {
            int r0 = __shfl(idx, j + half, 64);
            int r1 = __shfl(idx, j + 2 + half, 64);
            int r2 = __shfl(idx, j + 4 + half, 64);
            int r3 = __shfl(idx, j + 6 + half, 64);
            f16x4 u0 = *(const f16x4*)(plane + (size_t)r0 * 128 + ch4);
            f16x4 u1 = *(const f16x4*)(plane + (size_t)r1 * 128 + ch4);
            f16x4 u2 = *(const f16x4*)(plane + (size_t)r2 * 128 + ch4);
            f16x4 u3 = *(const f16x4*)(plane + (size_t)r3 * 128 + ch4);
            if (j + half < m)     { ax += (float)u0[0]; ay += (float)u0[1]; az += (float)u0[2]; aw += (float)u0[3]; }
            if (j + 2 + half < m) { ax += (float)u1[0]; ay += (float)u1[1]; az += (float)u1[2]; aw += (float)u1[3]; }
            if (j + 4 + half < m) { ax += (float)u2[0]; ay += (float)u2[1]; az += (float)u2[2]; aw += (float)u2[3]; }
            if (j + 6 + half < m) { ax += (float)u3[0]; ay += (float)u3[1]; az += (float)u3[2]; aw += (float)u3[3]; }
        }
    }
    ax += __shfl(ax, lane ^ 32, 64);
    ay += __shfl(ay, lane ^ 32, 64);
    az += __shfl(az, lane ^ 32, 64);
    aw += __shfl(aw, lane ^ 32, 64);
    if (half == 0) {
        u16x4 hi, lo;
        ushort_t h;
        h = f2bf(ax); hi[0] = h; lo[0] = f2bf(ax - bf2f(h));
        h = f2bf(ay); hi[1] = h; lo[1] = f2bf(ay - bf2f(h));
        h = f2bf(az); hi[2] = h; lo[2] = f2bf(az - bf2f(h));
        h = f2bf(aw); hi[3] = h; lo[3] = f2bf(aw - bf2f(h));
        size_t o = (size_t)node * 128 + ch4;
        *(u16x4*)(out_hi + o) = hi;
        *(u16x4*)(out_lo + o) = lo;
    }
}

// ---------------- fused MLP: ONE 32-row tile per block, grid = ntiles ----------------
// LDS 32KB (A 16KB + h1 16KB) -> ~4 blocks/CU co-resident; each block's 16KB
// global_load_lds prefetch overlaps other blocks' compute (TLP latency hiding).
// W fragments read coalesced from fragment-order planes (16B/lane runs).
__global__ __launch_bounds__(256) void k_mlp(const ushort_t* __restrict__ a_hi, const ushort_t* __restrict__ a_lo,
                                             const ushort_t* __restrict__ w1pl, const ushort_t* __restrict__ w2pl,
                                             const float* __restrict__ bias1, const float* __restrict__ bias2,
                                             float* __restrict__ h2, float* __restrict__ stats, int M) {
    __shared__ ushort_t lds_a[8192];    // [hi 4096 u16][lo 4096 u16], chunk-XOR swizzled
    __shared__ ushort_t lds_h1[8192];
    int tid = threadIdx.x;
    int lane = tid & 63;
    int wv = tid >> 6;
    int li = lane & 31, half = lane >> 5;
    int col = (wv << 5) + li;
    int rsw = li & 15;
    int m0 = blockIdx.x << 5;

    // stage A tile (16KB): 16 wave-uniform 1KB units; linear LDS dest, inverse-swizzled
    // global source (rule #21). Wave w issues units w, w+4, w+8, w+12.
#pragma unroll
    for (int i = 0; i < 4; ++i) {
        int u = wv + (i << 2);
        int ob = (u << 10) + (lane << 4);     // this lane's LDS byte
        int plane = ob >> 13;
        int r = (ob >> 8) & 31;
        int csw = (ob >> 4) & 15;
        int c = csw ^ (r & 15);
        int row = m0 + r; if (row >= M) row = M - 1;
        const ushort_t* g = (plane ? a_lo : a_hi) + (((size_t)row) << 7) + (c << 3);
        __builtin_amdgcn_global_load_lds(g, lds_a + (u << 9), 16, 0, 0);
    }

    // W1 fragments (coalesced) + biases — compiler-managed waits
    s16x8 b1h[8], b1l[8];
#pragma unroll
    for (int ks = 0; ks < 8; ++ks) {
        int fo = ((((wv << 3) + ks) << 6) + lane) << 3;
        b1h[ks] = *(const s16x8*)(w1pl + fo);
        b1l[ks] = *(const s16x8*)(w1pl + 16384 + fo);
    }
    float b1v = bias1[col], b2v = bias2[col];

    asm volatile("s_waitcnt vmcnt(0)" ::: "memory");   // A tile landed
    __builtin_amdgcn_sched_barrier(0);
    __builtin_amdgcn_s_barrier();

    // GEMM1: A from LDS (swizzled reads), W1 in regs
    f32x16 acc = {}, acc2 = {};
#pragma unroll
    for (int ks = 0; ks < 8; ++ks) {
        int csw = ((ks << 1) + half) ^ rsw;
        s16x8 ah = *(const s16x8*)(lds_a + (li << 7) + (csw << 3));
        s16x8 al = *(const s16x8*)(lds_a + 4096 + (li << 7) + (csw << 3));
        acc  = __builtin_amdgcn_mfma_f32_32x32x16_bf16(ah, b1h[ks], acc, 0, 0, 0);
        acc2 = __builtin_amdgcn_mfma_f32_32x32x16_bf16(ah, b1l[ks], acc2, 0, 0, 0);
        acc2 = __builtin_amdgcn_mfma_f32_32x32x16_bf16(al, b1h[ks], acc2, 0, 0, 0);
    }
    // epilogue 1: bias+relu, bf16 hi/lo split, swizzled LDS write
    int cch = col >> 3, cw = col & 7;
#pragma unroll
    for (int r = 0; r < 16; ++r) {
        int row = (r & 3) + ((r >> 2) << 3) + (half << 2);
        float v = fmaxf(acc[r] + acc2[r] + b1v, 0.f);
        ushort_t hh = f2bf(v);
        ushort_t ll = f2bf(v - bf2f(hh));
        int o = (row << 7) + ((cch ^ (row & 15)) << 3) + cw;
        lds_h1[o] = hh;
        lds_h1[4096 + o] = ll;
    }
    asm volatile("s_waitcnt lgkmcnt(0)" ::: "memory");
    __builtin_amdgcn_sched_barrier(0);
    __builtin_amdgcn_s_barrier();

    // GEMM2: h1 from LDS, W2 fragments loaded coalesced inline (L1/L2-hot)
    acc = (f32x16){}; acc2 = (f32x16){};
#pragma unroll
    for (int ks = 0; ks < 8; ++ks) {
        int csw = ((ks << 1) + half) ^ rsw;
        s16x8 ah = *(const s16x8*)(lds_h1 + (li << 7) + (csw << 3));
        s16x8 al = *(const s16x8*)(lds_h1 + 4096 + (li << 7) + (csw << 3));
        int fo = ((((wv << 3) + ks) << 6) + lane) << 3;
        s16x8 b2h = *(const s16x8*)(w2pl + fo);
        s16x8 b2l = *(const s16x8*)(w2pl + 16384 + fo);
        acc  = __builtin_amdgcn_mfma_f32_32x32x16_bf16(ah, b2h, acc, 0, 0, 0);
        acc2 = __builtin_amdgcn_mfma_f32_32x32x16_bf16(ah, b2l, acc2, 0, 0, 0);
        acc2 = __builtin_amdgcn_mfma_f32_32x32x16_bf16(al, b2h, acc2, 0, 0, 0);
    }
    // epilogue 2: bias, f32 store, stats
    float ssum = 0.f, ssq = 0.f;
#pragma unroll
    for (int r = 0; r < 16; ++r) {
        int row = m0 + (r & 3) + ((r >> 2) << 3) + (half << 2);
        if (row < M) {
            float v = acc[r] + acc2[r] + b2v;
            h2[(size_t)row * 128 + col] = v;
            ssum += v; ssq += v * v;
        }
    }
    ssum += __shfl(ssum, lane ^ 32, 64);
    ssq  += __shfl(ssq,  lane ^ 32, 64);
    if (half == 0) {
        atomicAdd(&stats[col], ssum);
        atomicAdd(&stats[128 + col], ssq);
    }
}

// ---------------- final BN + ReLU ----------------
__global__ __launch_bounds__(256) void k_bnapply(const float* __restrict__ h2, const float* __restrict__ stats,
                                                 const float* __restrict__ gamma, const float* __restrict__ beta,
                                                 float invN, float* __restrict__ out, int n4) {
    __shared__ float sc[128], sh[128];
    int t = threadIdx.x;
    if (t < 128) {
        float mean = stats[t] * invN;
        float var = stats[128 + t] * invN - mean * mean;
        float s = gamma[t] * rsqrtf(var + BN_EPS);
        sc[t] = s; sh[t] = beta[t] - mean * s;
    }
    __syncthreads();
    int i = blockIdx.x * 256 + t, st = gridDim.x * 256;
    for (; i < n4; i += st) {
        float4 v = ((const float4*)h2)[i];
        int c = (i << 2) & 127;
        v.x = fmaxf(v.x * sc[c + 0] + sh[c + 0], 0.f);
        v.y = fmaxf(v.y * sc[c + 1] + sh[c + 1], 0.f);
        v.z = fmaxf(v.z * sc[c + 2] + sh[c + 2], 0.f);
        v.w = fmaxf(v.w * sc[c + 3] + sh[c + 3], 0.f);
        ((float4*)out)[i] = v;
    }
}

extern "C" void kernel_launch(void* const* d_in, const int* in_sizes, int n_in,
                              void* d_out, int out_size, void* d_ws, size_t ws_size,
                              hipStream_t stream) {
    const float* x      = (const float*)d_in[0];
    const int*   ei     = (const int*)d_in[1];
    const float* w1_0   = (const float*)d_in[2];
    const float* b1_0   = (const float*)d_in[3];
    const float* w2_0   = (const float*)d_in[4];
    const float* b2_0   = (const float*)d_in[5];
    const float* gamma0 = (const float*)d_in[6];
    const float* beta0  = (const float*)d_in[7];
    const float* w1_1   = (const float*)d_in[8];
    const float* b1_1   = (const float*)d_in[9];
    const float* w2_1   = (const float*)d_in[10];
    const float* b2_1   = (const float*)d_in[11];
    const float* gamma1 = (const float*)d_in[12];
    const float* beta1  = (const float*)d_in[13];

    const int N = in_sizes[0] / 128;
    const int E = in_sizes[1] / 2;
    const int* srcI = ei;
    const int* dstI = ei + E;
    const int NBUK = (N + 1023) >> 10;                       // 98 (<=128 required)
    const int CAP  = (((E / NBUK) + 2048) + 255) & ~255;     // 16σ slack, uniform dst

    char* p = (char*)d_ws;
    auto aup = [](size_t v) { return (v + 255) & ~(size_t)255; };
    ushort_t* a_hi   = (ushort_t*)p; p += aup((size_t)N * 128 * 2);
    ushort_t* a_lo   = (ushort_t*)p; p += aup((size_t)N * 128 * 2);
    float*    h2     = (float*)p;    p += aup((size_t)N * 128 * 4);
    f16*      xh     = (f16*)p;      p += aup((size_t)N * 128 * 2);   // fp16 gather plane (reused for layer 1)
    int*      rowstart = (int*)p;    p += aup((size_t)(N + 1) * 4);
    int*      csr    = (int*)p;      p += aup((size_t)E * 4);
    uint32_t* binned = (uint32_t*)p; p += aup((size_t)NBUK * CAP * 4);
    ushort_t* wpl    = (ushort_t*)p; p += aup((size_t)4 * 32768 * 2);
    int*      bucketBase = (int*)p;  p += 512;
    int*      gcursor = (int*)p;                      // zero region: 512B cursors + 2KB stats
    float*    stats0  = (float*)(p + 512);
    float*    stats1  = stats0 + 256;
    hipMemsetAsync(gcursor, 0, 512 + 2048, stream);

    const int ntiles = (N + 31) / 32;
    const float invN = 1.0f / (float)N;
    float* out = (float*)d_out;

    k_wprep<<<256, 256, 0, stream>>>(w1_0, w2_0, w1_1, w2_1, wpl);
    k_x0<<<2048, 256, 0, stream>>>(x, xh, N * 32);
    k_bin<<<(E + CHUNK - 1) / CHUNK, 256, 0, stream>>>(srcI, dstI, E, NBUK, CAP, gcursor, binned);
    k_bucketscan<<<1, 128, 0, stream>>>(gcursor, NBUK, bucketBase, rowstart, N, E);
    k_bucketcsr<<<NBUK, 1024, 0, stream>>>(binned, gcursor, bucketBase, CAP, N, rowstart, csr);

    int aggBlocks = (N + 3) / 4;
    // ---- layer 0 ----
    k_agg<<<aggBlocks, 256, 0, stream>>>(xh, N, rowstart, csr, a_hi, a_lo);
    k_mlp<<<ntiles, 256, 0, stream>>>(a_hi, a_lo, wpl, wpl + 32768, b1_0, b2_0, h2, stats0, N);
    // ---- layer 1: BN+ReLU folded into fp16 plane prep; gather is pure fp16 ----
    k_x1<<<2048, 256, 0, stream>>>(h2, stats0, gamma0, beta0, invN, xh, N * 32);
    k_agg<<<aggBlocks, 256, 0, stream>>>(xh, N, rowstart, csr, a_hi, a_lo);
    k_mlp<<<ntiles, 256, 0, stream>>>(a_hi, a_lo, wpl + 65536, wpl + 98304, b1_1, b2_1, h2, stats1, N);
    k_bnapply<<<2048, 256, 0, stream>>>(h2, stats1, gamma1, beta1, invN, out, N * 32);
}